// Round 7
// baseline (338.202 us; speedup 1.0000x reference)
//
#include <hip/hip_runtime.h>

#define B_TOT 16384
#define DIMN  4096
#define EPSF  1e-10f

__device__ __forceinline__ void normalize8(float* rr, float* ii) {
  float n2 = 0.f;
#pragma unroll
  for (int q = 0; q < 8; q++) n2 += rr[q] * rr[q] + ii[q] * ii[q];
  float n = sqrtf(n2);
  if (n < EPSF) {
#pragma unroll
    for (int q = 0; q < 8; q++) { rr[q] = 0.f; ii[q] = 0.f; }
    rr[0] = 1.f;
  } else {
    float inv = 1.f / n;
#pragma unroll
    for (int q = 0; q < 8; q++) { rr[q] *= inv; ii[q] *= inv; }
  }
}

#define DOT8(a, b, wA, wB, p)                                              \
  fmaf((a).x, (wA).x, fmaf((a).y, (wA).y, fmaf((a).z, (wA).z,              \
  fmaf((a).w, (wA).w, fmaf((b).x, (wB).x, fmaf((b).y, (wB).y,              \
  fmaf((b).z, (wB).z, fmaf((b).w, (wB).w, (p)))))))))

// Fused enc GEMM + evolve + metrics + decode.
// 2048 blocks x 256 thr (4 waves). Block = 8 rows, wave = 2 rows, lane = K-slice.
// W_enc read per-lane from L2 (no LDS, no barriers in GEMM loop).
__global__ __launch_bounds__(256, 4) void k_fused(
    const float* __restrict__ x, const float* __restrict__ wenc,
    const float* __restrict__ benc, const float* __restrict__ phase,
    const float* __restrict__ disorder, const float* __restrict__ wdec,
    const float* __restrict__ bdec, float* __restrict__ out,
    float* __restrict__ blocksum) {
  __shared__ float absL[64];                   // 8 rows x 8 |amp|
  __shared__ float metL[24];                   // 8 rows x {purity, coh, ent}
  const int t = threadIdx.x;
  const int l = t & 63;
  const int wv = t >> 6;
  const int r0 = blockIdx.x * 8;
  const int row0 = r0 + wv * 2;

  const float* __restrict__ xr0 = x + (size_t)row0 * DIMN;
  const float* __restrict__ xr1 = xr0 + DIMN;

  float acc[2][16];
#pragma unroll
  for (int j = 0; j < 2; j++)
#pragma unroll
    for (int f = 0; f < 16; f++) acc[j][f] = 0.f;

  const int la = l * 4;                        // lane K-offset (slice A); B = +256
  // register double-buffer for x chunk loads
  float4 pa0 = *reinterpret_cast<const float4*>(xr0 + la);
  float4 pb0 = *reinterpret_cast<const float4*>(xr0 + la + 256);
  float4 pa1 = *reinterpret_cast<const float4*>(xr1 + la);
  float4 pb1 = *reinterpret_cast<const float4*>(xr1 + la + 256);

  for (int c = 0; c < 8; ++c) {                // K chunks of 512, barrier-free
    float4 xa0 = pa0, xb0 = pb0, xa1 = pa1, xb1 = pb1;
    if (c < 7) {
      const int n = (c + 1) * 512 + la;
      pa0 = *reinterpret_cast<const float4*>(xr0 + n);
      pb0 = *reinterpret_cast<const float4*>(xr0 + n + 256);
      pa1 = *reinterpret_cast<const float4*>(xr1 + n);
      pb1 = *reinterpret_cast<const float4*>(xr1 + n + 256);
    }
    const float* __restrict__ wc = wenc + c * 512 + la;   // L2-resident
#pragma unroll
    for (int f = 0; f < 16; ++f) {
      float4 wa = *reinterpret_cast<const float4*>(wc + (size_t)f * DIMN);
      float4 wb = *reinterpret_cast<const float4*>(wc + (size_t)f * DIMN + 256);
      acc[0][f] = DOT8(xa0, xb0, wa, wb, acc[0][f]);
      acc[1][f] = DOT8(xa1, xb1, wa, wb, acc[1][f]);
    }
  }

  // cross-lane butterfly reduce (all 32 accs), no LDS
#pragma unroll
  for (int off = 1; off < 64; off <<= 1) {
#pragma unroll
    for (int j = 0; j < 2; j++)
#pragma unroll
      for (int f = 0; f < 16; f++) acc[j][f] += __shfl_xor(acc[j][f], off);
  }

  // evolve: lanes 0-31 -> row0, lanes 32-63 -> row1 (redundant within half-wave)
  {
    const int half = l >> 5;
    const int r = row0 + half;
    float e[16];
#pragma unroll
    for (int k = 0; k < 16; k++)
      e[k] = tanhf((half ? acc[1][k] : acc[0][k]) + benc[k]);

    float re[8], im[8];
#pragma unroll
    for (int q = 0; q < 8; q++) {
      float ph = 0.1f * phase[q];
      float cc = cosf(ph), ss = sinf(ph);
      re[q] = e[q] * cc - e[8 + q] * ss + 0.017677669529663688f;  // +0.05/sqrt(8)
      im[q] = e[q] * ss + e[8 + q] * cc;
    }
    normalize8(re, im);

    float dd0 = disorder[0], dd1 = disorder[1], dd2 = disorder[2];
    float hz[8];
#pragma unroll
    for (int i = 0; i < 8; i++)
      hz[i] = ((i & 4) ? -dd0 : dd0) + ((i & 2) ? -dd1 : dd1) + ((i & 1) ? -dd2 : dd2);

#pragma unroll
    for (int step = 0; step < 2; step++) {
      float tt = 0.02f * (float)r + 0.01f * (float)step;
      float drive = 0.5f + 0.2f * sinf(1.61803398874989485f * tt);
      float nr[8], ni[8];
#pragma unroll
      for (int j = 0; j < 8; j++) {
        float hr = drive * (re[j ^ 1] + re[j ^ 2] + re[j ^ 4]) + hz[j] * re[j];
        float hi = drive * (im[j ^ 1] + im[j ^ 2] + im[j ^ 4]) + hz[j] * im[j];
        nr[j] = re[j] + 1e-4f * hi;            // amps - 1j*1e-4*Ha
        ni[j] = im[j] - 1e-4f * hr;
      }
      normalize8(nr, ni);
#pragma unroll
      for (int j = 0; j < 8; j++) { re[j] = nr[j]; im[j] = ni[j]; }
    }

    float tr = 0.f, s2 = 0.f;
    float ab[8];
#pragma unroll
    for (int q = 0; q < 8; q++) {
      float a2 = re[q] * re[q] + im[q] * im[q];
      tr += a2; s2 += a2 * a2;
      ab[q] = sqrtf(a2);
    }
    if ((l & 31) == 0) {
      const int ri = wv * 2 + half;
#pragma unroll
      for (int q = 0; q < 8; q++) absL[ri * 8 + q] = ab[q];
      float trp = tr + EPSF;
      float lam = fminf(fmaxf(tr / trp, EPSF), 1.f);   // rho rank-1
      float denom = lam + 8.f * EPSF;
      float e1 = lam / denom, er = EPSF / denom;
      metL[ri * 3 + 0] = tr * tr / (trp * trp);
      metL[ri * 3 + 1] = sqrtf(fmaxf(tr * tr - s2, 0.f)) / trp;
      metL[ri * 3 + 2] = -(e1 * log2f(e1 + EPSF) + 7.f * er * log2f(er + EPSF));
    }
  }
  __syncthreads();

  if (t == 0) {
    float s0 = 0.f, s1 = 0.f, s2 = 0.f;
#pragma unroll
    for (int ri = 0; ri < 8; ri++) {
      s0 += metL[ri * 3 + 0]; s1 += metL[ri * 3 + 1]; s2 += metL[ri * 3 + 2];
    }
    blocksum[blockIdx.x * 3 + 0] = s0;
    blocksum[blockIdx.x * 3 + 1] = s1;
    blocksum[blockIdx.x * 3 + 2] = s2;
  }

  // decode: 8 rows x 4096 cols; wdec register-cached (L2), coalesced f4 stores
#pragma unroll
  for (int g = 0; g < 4; ++g) {
    const int c4 = g * 1024 + t * 4;
    float wd[4][8];
#pragma unroll
    for (int j = 0; j < 4; ++j) {
      float4 a = *reinterpret_cast<const float4*>(wdec + (size_t)(c4 + j) * 8);
      float4 b = *reinterpret_cast<const float4*>(wdec + (size_t)(c4 + j) * 8 + 4);
      wd[j][0] = a.x; wd[j][1] = a.y; wd[j][2] = a.z; wd[j][3] = a.w;
      wd[j][4] = b.x; wd[j][5] = b.y; wd[j][6] = b.z; wd[j][7] = b.w;
    }
    float4 bd = *reinterpret_cast<const float4*>(bdec + c4);
#pragma unroll
    for (int r = 0; r < 8; ++r) {
      float4 a0 = *reinterpret_cast<const float4*>(&absL[r * 8]);     // broadcast
      float4 a1 = *reinterpret_cast<const float4*>(&absL[r * 8 + 4]);
      float aq[8] = {a0.x, a0.y, a0.z, a0.w, a1.x, a1.y, a1.z, a1.w};
      float o0 = bd.x, o1 = bd.y, o2 = bd.z, o3 = bd.w;
#pragma unroll
      for (int q = 0; q < 8; ++q) {
        o0 = fmaf(aq[q], wd[0][q], o0);
        o1 = fmaf(aq[q], wd[1][q], o1);
        o2 = fmaf(aq[q], wd[2][q], o2);
        o3 = fmaf(aq[q], wd[3][q], o3);
      }
      *reinterpret_cast<float4*>(out + (size_t)(r0 + r) * DIMN + c4) =
          make_float4(o0, o1, o2, o3);
    }
  }
}

// finalize metric means (2048 block partials)
__global__ void k_final(const float* __restrict__ blocksum,
                        float* __restrict__ out) {
  const int t = threadIdx.x;
  float s0 = 0.f, s1 = 0.f, s2 = 0.f;
  for (int b = t; b < 2048; b += 64) {
    s0 += blocksum[b * 3 + 0];
    s1 += blocksum[b * 3 + 1];
    s2 += blocksum[b * 3 + 2];
  }
#pragma unroll
  for (int off = 32; off > 0; off >>= 1) {
    s0 += __shfl_down(s0, off);
    s1 += __shfl_down(s1, off);
    s2 += __shfl_down(s2, off);
  }
  if (t == 0) {
    out[(size_t)B_TOT * DIMN + 0] = s0 / 16384.f;
    out[(size_t)B_TOT * DIMN + 1] = s1 / 16384.f;
    out[(size_t)B_TOT * DIMN + 2] = s2 / 16384.f;
  }
}

extern "C" void kernel_launch(void* const* d_in, const int* in_sizes, int n_in,
                              void* d_out, int out_size, void* d_ws, size_t ws_size,
                              hipStream_t stream) {
  const float *x = nullptr, *wenc = nullptr, *benc = nullptr, *phase = nullptr,
              *wdec = nullptr, *bdec = nullptr, *dis = nullptr;
  for (int i = 0; i < n_in; i++) {
    switch (in_sizes[i]) {
      case 67108864: x = (const float*)d_in[i]; break;      // 16384*4096
      case 65536:    wenc = (const float*)d_in[i]; break;   // 16*4096
      case 16:       benc = (const float*)d_in[i]; break;
      case 8:        phase = (const float*)d_in[i]; break;
      case 32768:    wdec = (const float*)d_in[i]; break;   // 4096*8
      case 4096:     bdec = (const float*)d_in[i]; break;
      case 3:        dis = (const float*)d_in[i]; break;
      default: break;
    }
  }

  float* bsum = (float*)d_ws;                  // 2048*3 floats
  float* out = (float*)d_out;

  hipLaunchKernelGGL(k_fused, dim3(2048), dim3(256), 0, stream,
                     x, wenc, benc, phase, dis, wdec, bdec, out, bsum);
  hipLaunchKernelGGL(k_final, dim3(1), dim3(64), 0, stream, bsum, out);
}

// Round 8
// 249.197 us; speedup vs baseline: 1.3572x; 1.3572x over previous
//
#include <hip/hip_runtime.h>

#define B_TOT 16384
#define DIMN  4096
#define EPSF  1e-10f

// ws layout (floats): absamp[16384*8] at 0, blocksum[1024*3] at 131072
#define ABS_OFF 0u
#define MET_OFF 131072u

__device__ __forceinline__ void normalize8(float* rr, float* ii) {
  float n2 = 0.f;
#pragma unroll
  for (int q = 0; q < 8; q++) n2 += rr[q] * rr[q] + ii[q] * ii[q];
  float n = sqrtf(n2);
  if (n < EPSF) {
#pragma unroll
    for (int q = 0; q < 8; q++) { rr[q] = 0.f; ii[q] = 0.f; }
    rr[0] = 1.f;
  } else {
    float inv = 1.f / n;
#pragma unroll
    for (int q = 0; q < 8; q++) { rr[q] *= inv; ii[q] *= inv; }
  }
}

#define DOT4(a, wA, p)                                                     \
  fmaf((a).x, (wA).x, fmaf((a).y, (wA).y, fmaf((a).z, (wA).z,              \
  fmaf((a).w, (wA).w, (p)))))

// K1: enc GEMM + evolve + metrics. 1024 blocks x 256 thr (4 waves).
// Wave owns 4 rows x all 16 features; lane owns K-slice [c*256+l*4 .. +3].
// W_enc per-lane from L2; 4 rows amortize L2 traffic to 4B-L2/1B-x.
__global__ __launch_bounds__(256, 4) void k_enc(
    const float* __restrict__ x, const float* __restrict__ wenc,
    const float* __restrict__ benc, const float* __restrict__ phase,
    const float* __restrict__ disorder, float* __restrict__ absamp,
    float* __restrict__ blocksum) {
  __shared__ float metL[48];                   // 16 rows x {purity, coh, ent}
  const int t = threadIdx.x;
  const int l = t & 63;
  const int wv = t >> 6;
  const int r0 = blockIdx.x * 16;
  const int row0 = r0 + wv * 4;

  const float* __restrict__ xr0 = x + (size_t)row0 * DIMN;
  const float* __restrict__ xr1 = xr0 + DIMN;
  const float* __restrict__ xr2 = xr1 + DIMN;
  const float* __restrict__ xr3 = xr2 + DIMN;

  float acc[4][16];
#pragma unroll
  for (int j = 0; j < 4; j++)
#pragma unroll
    for (int f = 0; f < 16; f++) acc[j][f] = 0.f;

  const int la = l * 4;                        // lane offset within 256-chunk
  float4 p0 = *reinterpret_cast<const float4*>(xr0 + la);
  float4 p1 = *reinterpret_cast<const float4*>(xr1 + la);
  float4 p2 = *reinterpret_cast<const float4*>(xr2 + la);
  float4 p3 = *reinterpret_cast<const float4*>(xr3 + la);

  for (int c = 0; c < 16; ++c) {               // K chunks of 256, barrier-free
    float4 x0 = p0, x1 = p1, x2 = p2, x3 = p3;
    if (c < 15) {
      const int n = (c + 1) * 256 + la;
      p0 = *reinterpret_cast<const float4*>(xr0 + n);
      p1 = *reinterpret_cast<const float4*>(xr1 + n);
      p2 = *reinterpret_cast<const float4*>(xr2 + n);
      p3 = *reinterpret_cast<const float4*>(xr3 + n);
    }
    const float* __restrict__ wc = wenc + c * 256 + la;   // L2-resident
#pragma unroll
    for (int f = 0; f < 16; ++f) {
      float4 wa = *reinterpret_cast<const float4*>(wc + (size_t)f * DIMN);
      acc[0][f] = DOT4(x0, wa, acc[0][f]);
      acc[1][f] = DOT4(x1, wa, acc[1][f]);
      acc[2][f] = DOT4(x2, wa, acc[2][f]);
      acc[3][f] = DOT4(x3, wa, acc[3][f]);
    }
  }

  // cross-lane butterfly reduce (64 accs), no LDS/barriers
#pragma unroll
  for (int off = 1; off < 64; off <<= 1) {
#pragma unroll
    for (int j = 0; j < 4; j++)
#pragma unroll
      for (int f = 0; f < 16; f++) acc[j][f] += __shfl_xor(acc[j][f], off);
  }

  // evolve: 16-lane group g16 = l>>4 handles row row0+g16 (redundant in group)
  {
    const int g16 = l >> 4;
    const int r = row0 + g16;
    float e[16];
#pragma unroll
    for (int k = 0; k < 16; k++) {
      float v01 = (g16 & 1) ? acc[1][k] : acc[0][k];   // static indices only
      float v23 = (g16 & 1) ? acc[3][k] : acc[2][k];
      e[k] = tanhf(((g16 & 2) ? v23 : v01) + benc[k]);
    }

    float re[8], im[8];
#pragma unroll
    for (int q = 0; q < 8; q++) {
      float ph = 0.1f * phase[q];
      float cc = cosf(ph), ss = sinf(ph);
      re[q] = e[q] * cc - e[8 + q] * ss + 0.017677669529663688f;  // +0.05/sqrt(8)
      im[q] = e[q] * ss + e[8 + q] * cc;
    }
    normalize8(re, im);

    float dd0 = disorder[0], dd1 = disorder[1], dd2 = disorder[2];
    float hz[8];
#pragma unroll
    for (int i = 0; i < 8; i++)
      hz[i] = ((i & 4) ? -dd0 : dd0) + ((i & 2) ? -dd1 : dd1) + ((i & 1) ? -dd2 : dd2);

#pragma unroll
    for (int step = 0; step < 2; step++) {
      float tt = 0.02f * (float)r + 0.01f * (float)step;
      float drive = 0.5f + 0.2f * sinf(1.61803398874989485f * tt);
      float nr[8], ni[8];
#pragma unroll
      for (int j = 0; j < 8; j++) {
        float hr = drive * (re[j ^ 1] + re[j ^ 2] + re[j ^ 4]) + hz[j] * re[j];
        float hi = drive * (im[j ^ 1] + im[j ^ 2] + im[j ^ 4]) + hz[j] * im[j];
        nr[j] = re[j] + 1e-4f * hi;            // amps - 1j*1e-4*Ha
        ni[j] = im[j] - 1e-4f * hr;
      }
      normalize8(nr, ni);
#pragma unroll
      for (int j = 0; j < 8; j++) { re[j] = nr[j]; im[j] = ni[j]; }
    }

    float tr = 0.f, s2 = 0.f;
    float ab[8];
#pragma unroll
    for (int q = 0; q < 8; q++) {
      float a2 = re[q] * re[q] + im[q] * im[q];
      tr += a2; s2 += a2 * a2;
      ab[q] = sqrtf(a2);
    }
    if ((l & 15) == 0) {
      const int ri = wv * 4 + g16;
      *reinterpret_cast<float4*>(absamp + (size_t)r * 8) =
          make_float4(ab[0], ab[1], ab[2], ab[3]);
      *reinterpret_cast<float4*>(absamp + (size_t)r * 8 + 4) =
          make_float4(ab[4], ab[5], ab[6], ab[7]);
      float trp = tr + EPSF;
      float lam = fminf(fmaxf(tr / trp, EPSF), 1.f);   // rho rank-1
      float denom = lam + 8.f * EPSF;
      float e1 = lam / denom, er = EPSF / denom;
      metL[ri * 3 + 0] = tr * tr / (trp * trp);
      metL[ri * 3 + 1] = sqrtf(fmaxf(tr * tr - s2, 0.f)) / trp;
      metL[ri * 3 + 2] = -(e1 * log2f(e1 + EPSF) + 7.f * er * log2f(er + EPSF));
    }
  }
  __syncthreads();

  if (t == 0) {
    float s0 = 0.f, s1 = 0.f, s2 = 0.f;
#pragma unroll
    for (int ri = 0; ri < 16; ri++) {
      s0 += metL[ri * 3 + 0]; s1 += metL[ri * 3 + 1]; s2 += metL[ri * 3 + 2];
    }
    blocksum[blockIdx.x * 3 + 0] = s0;
    blocksum[blockIdx.x * 3 + 1] = s1;
    blocksum[blockIdx.x * 3 + 2] = s2;
  }
}

// K2: dedicated decode (round-5 proven clean-write kernel).
// out[r][c] = sum_q absamp[r][q]*W_dec[c][q] + b_dec[c]
__global__ __launch_bounds__(256) void k_out(const float* __restrict__ absamp,
                                             const float* __restrict__ wdec,
                                             const float* __restrict__ bdec,
                                             float* __restrict__ out) {
  const int t = threadIdx.x;
  const int r0 = blockIdx.x * 64;
  const int c0 = blockIdx.y * 1024 + t * 4;
  float wv[4][8];
#pragma unroll
  for (int j = 0; j < 4; j++) {
    float4 a = *reinterpret_cast<const float4*>(wdec + (size_t)(c0 + j) * 8);
    float4 b = *reinterpret_cast<const float4*>(wdec + (size_t)(c0 + j) * 8 + 4);
    wv[j][0] = a.x; wv[j][1] = a.y; wv[j][2] = a.z; wv[j][3] = a.w;
    wv[j][4] = b.x; wv[j][5] = b.y; wv[j][6] = b.z; wv[j][7] = b.w;
  }
  float4 bd = *reinterpret_cast<const float4*>(bdec + c0);

  __shared__ float as_[512];                    // 64 rows x 8 q
  float2 av = *reinterpret_cast<const float2*>(absamp + (size_t)r0 * 8 + t * 2);
  as_[t * 2] = av.x; as_[t * 2 + 1] = av.y;
  __syncthreads();

  for (int r = 0; r < 64; r++) {
    float o0 = bd.x, o1 = bd.y, o2 = bd.z, o3 = bd.w;
#pragma unroll
    for (int q = 0; q < 8; q++) {
      float aq = as_[r * 8 + q];                // uniform -> broadcast
      o0 = fmaf(aq, wv[0][q], o0);
      o1 = fmaf(aq, wv[1][q], o1);
      o2 = fmaf(aq, wv[2][q], o2);
      o3 = fmaf(aq, wv[3][q], o3);
    }
    *reinterpret_cast<float4*>(out + (size_t)(r0 + r) * DIMN + c0) =
        make_float4(o0, o1, o2, o3);
  }
}

// K3: finalize metric means (1024 block partials)
__global__ void k_final(const float* __restrict__ blocksum,
                        float* __restrict__ out) {
  const int t = threadIdx.x;
  float s0 = 0.f, s1 = 0.f, s2 = 0.f;
  for (int b = t; b < 1024; b += 64) {
    s0 += blocksum[b * 3 + 0];
    s1 += blocksum[b * 3 + 1];
    s2 += blocksum[b * 3 + 2];
  }
#pragma unroll
  for (int off = 32; off > 0; off >>= 1) {
    s0 += __shfl_down(s0, off);
    s1 += __shfl_down(s1, off);
    s2 += __shfl_down(s2, off);
  }
  if (t == 0) {
    out[(size_t)B_TOT * DIMN + 0] = s0 / 16384.f;
    out[(size_t)B_TOT * DIMN + 1] = s1 / 16384.f;
    out[(size_t)B_TOT * DIMN + 2] = s2 / 16384.f;
  }
}

extern "C" void kernel_launch(void* const* d_in, const int* in_sizes, int n_in,
                              void* d_out, int out_size, void* d_ws, size_t ws_size,
                              hipStream_t stream) {
  const float *x = nullptr, *wenc = nullptr, *benc = nullptr, *phase = nullptr,
              *wdec = nullptr, *bdec = nullptr, *dis = nullptr;
  for (int i = 0; i < n_in; i++) {
    switch (in_sizes[i]) {
      case 67108864: x = (const float*)d_in[i]; break;      // 16384*4096
      case 65536:    wenc = (const float*)d_in[i]; break;   // 16*4096
      case 16:       benc = (const float*)d_in[i]; break;
      case 8:        phase = (const float*)d_in[i]; break;
      case 32768:    wdec = (const float*)d_in[i]; break;   // 4096*8
      case 4096:     bdec = (const float*)d_in[i]; break;
      case 3:        dis = (const float*)d_in[i]; break;
      default: break;
    }
  }

  float* ws = (float*)d_ws;
  float* absamp = ws + ABS_OFF;
  float* bsum   = ws + MET_OFF;
  float* out = (float*)d_out;

  hipLaunchKernelGGL(k_enc, dim3(1024), dim3(256), 0, stream,
                     x, wenc, benc, phase, dis, absamp, bsum);
  hipLaunchKernelGGL(k_out, dim3(256, 4), dim3(256), 0, stream,
                     absamp, wdec, bdec, out);
  hipLaunchKernelGGL(k_final, dim3(1), dim3(64), 0, stream, bsum, out);
}

// Round 9
// 248.272 us; speedup vs baseline: 1.3622x; 1.0037x over previous
//
#include <hip/hip_runtime.h>

#define B_TOT 16384
#define DIMN  4096
#define EPSF  1e-10f

// ws layout (floats): absamp[16384*8] at 0, blocksum[1024*3] at 131072
#define ABS_OFF 0u
#define MET_OFF 131072u

__device__ __forceinline__ void normalize8(float* rr, float* ii) {
  float n2 = 0.f;
#pragma unroll
  for (int q = 0; q < 8; q++) n2 += rr[q] * rr[q] + ii[q] * ii[q];
  float n = sqrtf(n2);
  if (n < EPSF) {
#pragma unroll
    for (int q = 0; q < 8; q++) { rr[q] = 0.f; ii[q] = 0.f; }
    rr[0] = 1.f;
  } else {
    float inv = 1.f / n;
#pragma unroll
    for (int q = 0; q < 8; q++) { rr[q] *= inv; ii[q] *= inv; }
  }
}

#define DOT4(a, wA, p)                                                     \
  fmaf((a).x, (wA).x, fmaf((a).y, (wA).y, fmaf((a).z, (wA).z,              \
  fmaf((a).w, (wA).w, (p)))))

// K1: enc GEMM + evolve + metrics. 1024 blocks x 256 thr (4 waves).
// Wave owns 4 rows x 16 features; lane owns K-slice. Barrier-free GEMM.
// __launch_bounds__(256,2): 128-VGPR budget -> acc[4][16] fits, NO spill.
__global__ __launch_bounds__(256, 2) void k_enc(
    const float* __restrict__ x, const float* __restrict__ wenc,
    const float* __restrict__ benc, const float* __restrict__ phase,
    const float* __restrict__ disorder, float* __restrict__ absamp,
    float* __restrict__ blocksum) {
  __shared__ float metL[48];                   // 16 rows x {purity, coh, ent}
  const int t = threadIdx.x;
  const int l = t & 63;
  const int wv = t >> 6;
  const int r0 = blockIdx.x * 16;
  const int row0 = r0 + wv * 4;

  const float* __restrict__ xr0 = x + (size_t)row0 * DIMN;
  const float* __restrict__ xr1 = xr0 + DIMN;
  const float* __restrict__ xr2 = xr1 + DIMN;
  const float* __restrict__ xr3 = xr2 + DIMN;

  float acc[4][16];
#pragma unroll
  for (int j = 0; j < 4; j++)
#pragma unroll
    for (int f = 0; f < 16; f++) acc[j][f] = 0.f;

  const int la = l * 4;                        // lane offset within 256-chunk
  float4 p0 = *reinterpret_cast<const float4*>(xr0 + la);
  float4 p1 = *reinterpret_cast<const float4*>(xr1 + la);
  float4 p2 = *reinterpret_cast<const float4*>(xr2 + la);
  float4 p3 = *reinterpret_cast<const float4*>(xr3 + la);

  for (int c = 0; c < 16; ++c) {               // K chunks of 256, barrier-free
    float4 x0 = p0, x1 = p1, x2 = p2, x3 = p3;
    if (c < 15) {
      const int n = (c + 1) * 256 + la;
      p0 = *reinterpret_cast<const float4*>(xr0 + n);
      p1 = *reinterpret_cast<const float4*>(xr1 + n);
      p2 = *reinterpret_cast<const float4*>(xr2 + n);
      p3 = *reinterpret_cast<const float4*>(xr3 + n);
    }
    const float* __restrict__ wc = wenc + c * 256 + la;   // L2-resident
#pragma unroll
    for (int f = 0; f < 16; ++f) {
      float4 wa = *reinterpret_cast<const float4*>(wc + (size_t)f * DIMN);
      acc[0][f] = DOT4(x0, wa, acc[0][f]);
      acc[1][f] = DOT4(x1, wa, acc[1][f]);
      acc[2][f] = DOT4(x2, wa, acc[2][f]);
      acc[3][f] = DOT4(x3, wa, acc[3][f]);
    }
  }

  // cross-lane butterfly reduce (64 accs), no LDS/barriers
#pragma unroll
  for (int off = 1; off < 64; off <<= 1) {
#pragma unroll
    for (int j = 0; j < 4; j++)
#pragma unroll
      for (int f = 0; f < 16; f++) acc[j][f] += __shfl_xor(acc[j][f], off);
  }

  // evolve: 16-lane group g16 = l>>4 handles row row0+g16 (redundant in group)
  {
    const int g16 = l >> 4;
    const int r = row0 + g16;
    float e[16];
#pragma unroll
    for (int k = 0; k < 16; k++) {
      float v01 = (g16 & 1) ? acc[1][k] : acc[0][k];   // static indices only
      float v23 = (g16 & 1) ? acc[3][k] : acc[2][k];
      e[k] = tanhf(((g16 & 2) ? v23 : v01) + benc[k]);
    }

    float re[8], im[8];
#pragma unroll
    for (int q = 0; q < 8; q++) {
      float ph = 0.1f * phase[q];
      float cc = cosf(ph), ss = sinf(ph);
      re[q] = e[q] * cc - e[8 + q] * ss + 0.017677669529663688f;  // +0.05/sqrt(8)
      im[q] = e[q] * ss + e[8 + q] * cc;
    }
    normalize8(re, im);

    float dd0 = disorder[0], dd1 = disorder[1], dd2 = disorder[2];
    float hz[8];
#pragma unroll
    for (int i = 0; i < 8; i++)
      hz[i] = ((i & 4) ? -dd0 : dd0) + ((i & 2) ? -dd1 : dd1) + ((i & 1) ? -dd2 : dd2);

#pragma unroll
    for (int step = 0; step < 2; step++) {
      float tt = 0.02f * (float)r + 0.01f * (float)step;
      float drive = 0.5f + 0.2f * sinf(1.61803398874989485f * tt);
      float nr[8], ni[8];
#pragma unroll
      for (int j = 0; j < 8; j++) {
        float hr = drive * (re[j ^ 1] + re[j ^ 2] + re[j ^ 4]) + hz[j] * re[j];
        float hi = drive * (im[j ^ 1] + im[j ^ 2] + im[j ^ 4]) + hz[j] * im[j];
        nr[j] = re[j] + 1e-4f * hi;            // amps - 1j*1e-4*Ha
        ni[j] = im[j] - 1e-4f * hr;
      }
      normalize8(nr, ni);
#pragma unroll
      for (int j = 0; j < 8; j++) { re[j] = nr[j]; im[j] = ni[j]; }
    }

    float tr = 0.f, s2 = 0.f;
    float ab[8];
#pragma unroll
    for (int q = 0; q < 8; q++) {
      float a2 = re[q] * re[q] + im[q] * im[q];
      tr += a2; s2 += a2 * a2;
      ab[q] = sqrtf(a2);
    }
    if ((l & 15) == 0) {
      const int ri = wv * 4 + g16;
      *reinterpret_cast<float4*>(absamp + (size_t)r * 8) =
          make_float4(ab[0], ab[1], ab[2], ab[3]);
      *reinterpret_cast<float4*>(absamp + (size_t)r * 8 + 4) =
          make_float4(ab[4], ab[5], ab[6], ab[7]);
      float trp = tr + EPSF;
      float lam = fminf(fmaxf(tr / trp, EPSF), 1.f);   // rho rank-1
      float denom = lam + 8.f * EPSF;
      float e1 = lam / denom, er = EPSF / denom;
      metL[ri * 3 + 0] = tr * tr / (trp * trp);
      metL[ri * 3 + 1] = sqrtf(fmaxf(tr * tr - s2, 0.f)) / trp;
      metL[ri * 3 + 2] = -(e1 * log2f(e1 + EPSF) + 7.f * er * log2f(er + EPSF));
    }
  }
  __syncthreads();

  if (t == 0) {
    float s0 = 0.f, s1 = 0.f, s2 = 0.f;
#pragma unroll
    for (int ri = 0; ri < 16; ri++) {
      s0 += metL[ri * 3 + 0]; s1 += metL[ri * 3 + 1]; s2 += metL[ri * 3 + 2];
    }
    blocksum[blockIdx.x * 3 + 0] = s0;
    blocksum[blockIdx.x * 3 + 1] = s1;
    blocksum[blockIdx.x * 3 + 2] = s2;
  }
}

// K2: dedicated decode (clean clustered writes: 268 MB exactly).
__global__ __launch_bounds__(256) void k_out(const float* __restrict__ absamp,
                                             const float* __restrict__ wdec,
                                             const float* __restrict__ bdec,
                                             float* __restrict__ out) {
  const int t = threadIdx.x;
  const int r0 = blockIdx.x * 64;
  const int c0 = blockIdx.y * 1024 + t * 4;
  float wv[4][8];
#pragma unroll
  for (int j = 0; j < 4; j++) {
    float4 a = *reinterpret_cast<const float4*>(wdec + (size_t)(c0 + j) * 8);
    float4 b = *reinterpret_cast<const float4*>(wdec + (size_t)(c0 + j) * 8 + 4);
    wv[j][0] = a.x; wv[j][1] = a.y; wv[j][2] = a.z; wv[j][3] = a.w;
    wv[j][4] = b.x; wv[j][5] = b.y; wv[j][6] = b.z; wv[j][7] = b.w;
  }
  float4 bd = *reinterpret_cast<const float4*>(bdec + c0);

  __shared__ float as_[512];                    // 64 rows x 8 q
  float2 av = *reinterpret_cast<const float2*>(absamp + (size_t)r0 * 8 + t * 2);
  as_[t * 2] = av.x; as_[t * 2 + 1] = av.y;
  __syncthreads();

  for (int r = 0; r < 64; r++) {
    float o0 = bd.x, o1 = bd.y, o2 = bd.z, o3 = bd.w;
#pragma unroll
    for (int q = 0; q < 8; q++) {
      float aq = as_[r * 8 + q];                // uniform -> broadcast
      o0 = fmaf(aq, wv[0][q], o0);
      o1 = fmaf(aq, wv[1][q], o1);
      o2 = fmaf(aq, wv[2][q], o2);
      o3 = fmaf(aq, wv[3][q], o3);
    }
    *reinterpret_cast<float4*>(out + (size_t)(r0 + r) * DIMN + c0) =
        make_float4(o0, o1, o2, o3);
  }
}

// K3: finalize metric means (1024 block partials)
__global__ void k_final(const float* __restrict__ blocksum,
                        float* __restrict__ out) {
  const int t = threadIdx.x;
  float s0 = 0.f, s1 = 0.f, s2 = 0.f;
  for (int b = t; b < 1024; b += 64) {
    s0 += blocksum[b * 3 + 0];
    s1 += blocksum[b * 3 + 1];
    s2 += blocksum[b * 3 + 2];
  }
#pragma unroll
  for (int off = 32; off > 0; off >>= 1) {
    s0 += __shfl_down(s0, off);
    s1 += __shfl_down(s1, off);
    s2 += __shfl_down(s2, off);
  }
  if (t == 0) {
    out[(size_t)B_TOT * DIMN + 0] = s0 / 16384.f;
    out[(size_t)B_TOT * DIMN + 1] = s1 / 16384.f;
    out[(size_t)B_TOT * DIMN + 2] = s2 / 16384.f;
  }
}

extern "C" void kernel_launch(void* const* d_in, const int* in_sizes, int n_in,
                              void* d_out, int out_size, void* d_ws, size_t ws_size,
                              hipStream_t stream) {
  const float *x = nullptr, *wenc = nullptr, *benc = nullptr, *phase = nullptr,
              *wdec = nullptr, *bdec = nullptr, *dis = nullptr;
  for (int i = 0; i < n_in; i++) {
    switch (in_sizes[i]) {
      case 67108864: x = (const float*)d_in[i]; break;      // 16384*4096
      case 65536:    wenc = (const float*)d_in[i]; break;   // 16*4096
      case 16:       benc = (const float*)d_in[i]; break;
      case 8:        phase = (const float*)d_in[i]; break;
      case 32768:    wdec = (const float*)d_in[i]; break;   // 4096*8
      case 4096:     bdec = (const float*)d_in[i]; break;
      case 3:        dis = (const float*)d_in[i]; break;
      default: break;
    }
  }

  float* ws = (float*)d_ws;
  float* absamp = ws + ABS_OFF;
  float* bsum   = ws + MET_OFF;
  float* out = (float*)d_out;

  hipLaunchKernelGGL(k_enc, dim3(1024), dim3(256), 0, stream,
                     x, wenc, benc, phase, dis, absamp, bsum);
  hipLaunchKernelGGL(k_out, dim3(256, 4), dim3(256), 0, stream,
                     absamp, wdec, bdec, out);
  hipLaunchKernelGGL(k_final, dim3(1), dim3(64), 0, stream, bsum, out);
}